// Round 7
// baseline (97.163 us; speedup 1.0000x reference)
//
#include <hip/hip_runtime.h>

typedef _Float16 f16;
typedef _Float16 f16x8 __attribute__((ext_vector_type(8)));
typedef float    f32x4 __attribute__((ext_vector_type(4)));

#define HO 62
#define WO 62

// Block = 256 thr (4 waves); grid = 256 planes x 8 row-chunks.
// Per block: feature map for 10 input rows in LDS (f16, 16 slots/pixel:
// slot0 = silu, 1..8 = cubic B-spline bases, rest zero), then per wave one
// 16-output-col tile x 8 output rows x 8 v via MFMA 16x16x32_f16 with
// rolling A-fragment reuse (rows shared across consecutive output rows).
__global__ __launch_bounds__(256, 4) void kan_conv_mfma2(
    const float* __restrict__ x,     // (256, 64, 64)
    const float* __restrict__ grid,  // (9, 12) uniform knots
    const float* __restrict__ bw,    // (8, 9)
    const float* __restrict__ sw,    // (8, 9, 8)
    const float* __restrict__ sc,    // (8, 9)
    float* __restrict__ out)         // (256*8, 62, 62)
{
    __shared__ __align__(16) f16 feat[10368];   // 10 rows * 1024 + zero tail

    const int tid  = threadIdx.x;
    const int lane = tid & 63;
    const int w    = tid >> 6;          // wave 0..3 = column tile

    const int bx    = blockIdx.x;       // 0..2047
    const int plane = bx >> 3;
    const int chunk = bx & 7;
    const int r0    = chunk * 8;        // output rows r0..r0+7 (masked >=62)

    // ---- constant B fragments (identical mapping to R6, which validated)
    const int nn = lane & 15;           // D col = v (A row = out col, same bits)
    const int kb = lane >> 4;           // 0..3
    f16x8 bfrag[3][2];
    #pragma unroll
    for (int ki = 0; ki < 3; ++ki) {
        #pragma unroll
        for (int kjp = 0; kjp < 2; ++kjp) {
            f16x8 bf;
            #pragma unroll
            for (int e = 0; e < 8; ++e) {
                const int k    = kb * 8 + e;
                const int kj   = kjp * 2 + (k >> 4);
                const int slot = k & 15;
                float wv = 0.0f;
                if (nn < 8 && kj < 3 && slot < 9) {
                    const int kk = ki * 3 + kj;
                    wv = (slot == 0) ? bw[nn * 9 + kk]
                                     : sw[(nn * 9 + kk) * 8 + (slot - 1)] * sc[nn * 9 + kk];
                }
                bf[e] = (f16)wv;
            }
            bfrag[ki][kjp] = bf;
        }
    }

    // ---- stage 1: feature map for input rows r0..r0+9 (clamped rows only
    //      feed store-masked outputs)
    const float g0    = grid[0];
    const float inv_h = 1.0f / (grid[1] - grid[0]);
    const float* xp   = x + (size_t)plane * 4096;

    for (int idx = tid; idx < 640; idx += 256) {
        const int row = idx >> 6;       // 0..9
        const int col = idx & 63;
        int gy = r0 + row; gy = (gy < 64) ? gy : 63;
        const float xv = xp[gy * 64 + col];

        const float s = xv / (1.0f + __expf(-xv));
        const float u = (xv - g0) * inv_h;
        int j = (int)floorf(u);
        j = (j < 3) ? 3 : ((j > 7) ? 7 : j);
        const float t   = u - (float)j;
        const float omt = 1.0f - t;
        const float t2  = t * t;
        const float t3  = t2 * t;
        const float c6  = 1.0f / 6.0f;
        float bv[4];
        bv[0] = omt * omt * omt * c6;
        bv[1] = (3.0f * t3 - 6.0f * t2 + 4.0f) * c6;
        bv[2] = (-3.0f * t3 + 3.0f * t2 + 3.0f * t + 1.0f) * c6;
        bv[3] = t3 * c6;

        const int base0 = row * 1024 + col * 8;
        f16x8 z0 = {(f16)s, (f16)0.f, (f16)0.f, (f16)0.f,
                    (f16)0.f, (f16)0.f, (f16)0.f, (f16)0.f};
        f16x8 z1 = {(f16)0.f, (f16)0.f, (f16)0.f, (f16)0.f,
                    (f16)0.f, (f16)0.f, (f16)0.f, (f16)0.f};
        *(f16x8*)&feat[base0]       = z0;
        *(f16x8*)&feat[base0 + 512] = z1;
        #pragma unroll
        for (int m = 0; m < 4; ++m) {
            const int slot = j - 2 + m;   // 1..8
            feat[row * 1024 + (slot >> 3) * 512 + col * 8 + (slot & 7)] = (f16)bv[m];
        }
    }
    // zero tail so edge-spill A-reads (paired with zero B rows) stay finite
    if (tid < 16) {
        f16x8 z = {(f16)0.f, (f16)0.f, (f16)0.f, (f16)0.f,
                   (f16)0.f, (f16)0.f, (f16)0.f, (f16)0.f};
        *(f16x8*)&feat[10240 + tid * 8] = z;
    }
    __syncthreads();

    // ---- stage 2: wave w -> cols c0..c0+15, output rows r0..r0+7
    const int mI    = lane & 15;
    const int khalf = kb & 1;
    const int cAdd  = kb >> 1;
    const int c0    = w * 16;
    // f16-index of A element: row*1024 + khalf*512 + col*8
    const int aBase = khalf * 512 + (c0 + mI + cAdd) * 8;

    f16x8 af[3][2];   // rolling A rows (row r lives at af[r % 3])
    #pragma unroll
    for (int kjp = 0; kjp < 2; ++kjp) {
        af[0][kjp] = *(const f16x8*)&feat[aBase + kjp * 16 + 0 * 1024];
        af[1][kjp] = *(const f16x8*)&feat[aBase + kjp * 16 + 1 * 1024];
    }

    #pragma unroll
    for (int i = 0; i < 8; ++i) {        // output row ro = i (u = w+4i -> ro=i)
        #pragma unroll
        for (int kjp = 0; kjp < 2; ++kjp)
            af[(i + 2) % 3][kjp] = *(const f16x8*)&feat[aBase + kjp * 16 + (i + 2) * 1024];

        f32x4 acc = {0.f, 0.f, 0.f, 0.f};
        #pragma unroll
        for (int ki = 0; ki < 3; ++ki) {
            #pragma unroll
            for (int kjp = 0; kjp < 2; ++kjp)
                acc = __builtin_amdgcn_mfma_f32_16x16x32_f16(
                          af[(i + ki) % 3][kjp], bfrag[ki][kjp], acc, 0, 0, 0);
        }

        // D[row = kb*4+q][col = nn]: row = out col, col = v
        const int ho = r0 + i;
        if (nn < 8 && ho < HO) {
            const int cb = c0 + kb * 4;
            float* po = out + ((size_t)(plane * 8 + nn) * (HO * WO)) + ho * WO + cb;
            if (cb + 3 < WO) {
                float2 lo = {acc[0], acc[1]};
                float2 hi = {acc[2], acc[3]};
                *(float2*)po       = lo;
                *(float2*)(po + 2) = hi;
            } else {
                #pragma unroll
                for (int q = 0; q < 4; ++q)
                    if (cb + q < WO) po[q] = acc[q];
            }
        }
    }
}

extern "C" void kernel_launch(void* const* d_in, const int* in_sizes, int n_in,
                              void* d_out, int out_size, void* d_ws, size_t ws_size,
                              hipStream_t stream) {
    const float* x    = (const float*)d_in[0];
    const float* grid = (const float*)d_in[1];
    const float* bw   = (const float*)d_in[2];
    const float* sw   = (const float*)d_in[3];
    const float* sc   = (const float*)d_in[4];
    float* out = (float*)d_out;

    kan_conv_mfma2<<<2048, 256, 0, stream>>>(x, grid, bw, sw, sc, out);
}

// Round 8
// 94.268 us; speedup vs baseline: 1.0307x; 1.0307x over previous
//
#include <hip/hip_runtime.h>

typedef _Float16 f16;
typedef _Float16 f16x8 __attribute__((ext_vector_type(8)));
typedef float    f32x4 __attribute__((ext_vector_type(4)));

#define HO 62
#define WO 62

// Barrier-free MFMA KAN conv. Grid = 2048 blocks (256 planes x 8 row-chunks),
// block = 256 thr = 4 INDEPENDENT waves. Wave w owns output cols w*16..w*16+15
// of its chunk and a private LDS slice; it builds features for its own
// 10-row x 18-col input tile (halo incl.), then MFMAs from its own slice.
// Same-wave ds_write->ds_read ordering is lgkmcnt-only: NO __syncthreads.
// Pixel record = 16 f16 slots (slot0 silu, 1..8 spline bases, 9..15 zero).
__global__ __launch_bounds__(256, 5) void kan_conv_nobar(
    const float* __restrict__ x,     // (256, 64, 64)
    const float* __restrict__ grid,  // (9, 12) uniform knots
    const float* __restrict__ bw,    // (8, 9)
    const float* __restrict__ sw,    // (8, 9, 8)
    const float* __restrict__ sc,    // (8, 9)
    float* __restrict__ out)         // (256*8, 62, 62)
{
    __shared__ __align__(16) f16 feat[4 * 2880];   // 4 waves x 10x18x16 f16 = 23 KB

    const int tid  = threadIdx.x;
    const int lane = tid & 63;
    const int w    = tid >> 6;
    f16* wfeat = &feat[w * 2880];

    const int bx    = blockIdx.x;
    const int plane = bx >> 3;
    const int chunk = bx & 7;
    const int r0    = chunk * 8;     // output rows r0..r0+7 (store-masked >=62)
    const int c0    = w * 16;        // output cols c0..c0+15

    // ---- constant B fragments (mapping validated in R6/R7)
    const int nn = lane & 15;        // D col = v; also A row = out col (same bits)
    const int kb = lane >> 4;        // 0..3
    f16x8 bfrag[3][2];
    #pragma unroll
    for (int ki = 0; ki < 3; ++ki) {
        #pragma unroll
        for (int kjp = 0; kjp < 2; ++kjp) {
            f16x8 bf;
            #pragma unroll
            for (int e = 0; e < 8; ++e) {
                const int k    = kb * 8 + e;
                const int kj   = kjp * 2 + (k >> 4);
                const int slot = k & 15;
                float wv = 0.0f;
                if (nn < 8 && kj < 3 && slot < 9) {
                    const int kk = ki * 3 + kj;
                    wv = (slot == 0) ? bw[nn * 9 + kk]
                                     : sw[(nn * 9 + kk) * 8 + (slot - 1)] * sc[nn * 9 + kk];
                }
                bf[e] = (f16)wv;
            }
            bfrag[ki][kjp] = bf;
        }
    }

    // ---- issue the 3 x-loads up-front (separate addr+load from use)
    const float* xp = x + (size_t)plane * 4096;
    float xv3[3];
    int   p3[3];
    #pragma unroll
    for (int it = 0; it < 3; ++it) {
        int p = it * 64 + lane;              // pixel index in 10x18 tile
        p3[it] = p;
        int row = p / 18;                    // magic-mul
        int col = p - row * 18;
        int gy = r0 + row; gy = (gy < 64) ? gy : 63;   // clamped rows/cols feed
        int gx = c0 + col; gx = (gx < 64) ? gx : 63;   // only masked outputs
        xv3[it] = xp[gy * 64 + gx];          // p>=180 lanes load garbage row; unused
    }

    const float g0    = grid[0];
    const float inv_h = 1.0f / (grid[1] - grid[0]);

    // ---- stage 1 (wave-private): features for 10 rows x 18 cols
    #pragma unroll
    for (int it = 0; it < 3; ++it) {
        const int p = p3[it];
        if (p < 180) {
            const float xv = xv3[it];
            const float s = xv / (1.0f + __expf(-xv));
            const float u = (xv - g0) * inv_h;
            int j = (int)floorf(u);
            j = (j < 3) ? 3 : ((j > 7) ? 7 : j);
            const float t   = u - (float)j;
            const float omt = 1.0f - t;
            const float t2  = t * t;
            const float t3  = t2 * t;
            const float c6  = 1.0f / 6.0f;
            float bv0 = omt * omt * omt * c6;
            float bv1 = (3.0f * t3 - 6.0f * t2 + 4.0f) * c6;
            float bv2 = (-3.0f * t3 + 3.0f * t2 + 3.0f * t + 1.0f) * c6;
            float bv3 = t3 * c6;

            f16* fp = &wfeat[p * 16];
            f16x8 z0 = {(f16)s, (f16)0.f, (f16)0.f, (f16)0.f,
                        (f16)0.f, (f16)0.f, (f16)0.f, (f16)0.f};
            f16x8 z1 = {(f16)0.f, (f16)0.f, (f16)0.f, (f16)0.f,
                        (f16)0.f, (f16)0.f, (f16)0.f, (f16)0.f};
            *(f16x8*)fp       = z0;          // slots 0-7
            *(f16x8*)(fp + 8) = z1;          // slots 8-15
            fp[j - 2] = (f16)bv0;            // scatter slots j-2..j+1 (1..8)
            fp[j - 1] = (f16)bv1;
            fp[j]     = (f16)bv2;
            fp[j + 1] = (f16)bv3;
        }
    }
    // NO __syncthreads — wave reads only its own writes (lgkmcnt ordering).

    // ---- stage 2: 8 output rows x 16 cols x 8 v via 6 MFMAs/row
    const int mI    = lane & 15;
    const int khalf = kb & 1;
    const int cAdd  = kb >> 1;
    // f16 offset of A element: (row*18 + tileCol)*16 + khalf*8
    const int aBase = (mI + cAdd) * 16 + khalf * 8;

    f16x8 af[3][2];                  // rolling A rows (row r at af[r % 3])
    #pragma unroll
    for (int kjp = 0; kjp < 2; ++kjp) {
        af[0][kjp] = *(const f16x8*)&wfeat[aBase + kjp * 32 + 0 * 288];
        af[1][kjp] = *(const f16x8*)&wfeat[aBase + kjp * 32 + 1 * 288];
    }

    #pragma unroll
    for (int i = 0; i < 8; ++i) {
        #pragma unroll
        for (int kjp = 0; kjp < 2; ++kjp)
            af[(i + 2) % 3][kjp] =
                *(const f16x8*)&wfeat[aBase + kjp * 32 + (i + 2) * 288];

        f32x4 acc = {0.f, 0.f, 0.f, 0.f};
        #pragma unroll
        for (int ki = 0; ki < 3; ++ki) {
            #pragma unroll
            for (int kjp = 0; kjp < 2; ++kjp)
                acc = __builtin_amdgcn_mfma_f32_16x16x32_f16(
                          af[(i + ki) % 3][kjp], bfrag[ki][kjp], acc, 0, 0, 0);
        }

        const int ho = r0 + i;
        if (nn < 8 && ho < HO) {
            const int cb = c0 + kb * 4;
            float* po = out + ((size_t)(plane * 8 + nn) * (HO * WO)) + ho * WO + cb;
            if (cb + 3 < WO) {
                float2 lo = {acc[0], acc[1]};
                float2 hi = {acc[2], acc[3]};
                *(float2*)po       = lo;
                *(float2*)(po + 2) = hi;
            } else {
                #pragma unroll
                for (int q = 0; q < 4; ++q)
                    if (cb + q < WO) po[q] = acc[q];
            }
        }
    }
}

extern "C" void kernel_launch(void* const* d_in, const int* in_sizes, int n_in,
                              void* d_out, int out_size, void* d_ws, size_t ws_size,
                              hipStream_t stream) {
    const float* x    = (const float*)d_in[0];
    const float* grid = (const float*)d_in[1];
    const float* bw   = (const float*)d_in[2];
    const float* sw   = (const float*)d_in[3];
    const float* sc   = (const float*)d_in[4];
    float* out = (float*)d_out;

    kan_conv_nobar<<<2048, 256, 0, stream>>>(x, grid, bw, sw, sc, out);
}